// Round 15
// baseline (82.386 us; speedup 1.0000x reference)
//
#include <hip/hip_runtime.h>

#define Bq 1024
#define Hq 2048
#define NOUTq 512

#define DECAYF 0.95122942450071400910f
#define THRF 0.4f
#define SINVF 5931641.0f            // 2^22.5-ish; |q| <= ~712K, digits fit i8

// d_out offsets (in floats), outputs concatenated in return order
#define OFF_OUT  0
#define OFF_Z    524288
#define OFF_V    2621440
#define OFF_R    4718592
#define OFF_TIN  6815744
#define OFF_TREC 8912896
#define OFF_DZ   11010048

// ws layout (bytes)
#define WS_A     0ul           // i8 [1024][4096]  (inputs | z)          4 MB
#define WS_Q0    4194304ul     // i8 W^T plane0 [2048][4096]             8 MB
#define WS_Q1    12582912ul    // i8 W^T plane1                          8 MB
#define WS_Q2    20971520ul    // i8 W^T plane2                          8 MB
#define WS_WOUTT 29360128ul    // bf16 w_out^T [512][2048]               2 MB
#define WS_P     31457280ul    // i32 partials [2][1024][2048] (16 MB used)
#define WS_Z2    65011712ul    // bf16 new_z [1024][2048]                4 MB
#define WS_NEED  69206016ul

typedef __attribute__((ext_vector_type(8))) short  bf16x8;
typedef __attribute__((ext_vector_type(4))) short  s16x4;
typedef __attribute__((ext_vector_type(4))) float  f32x4;
typedef __attribute__((ext_vector_type(4))) int    i32x4;
typedef __attribute__((ext_vector_type(4))) char   c8x4;

// T3/T4 pipeline fences (rule #18: memory clobber + sched_barrier around waits)
#define VMCNT8  asm volatile("s_waitcnt vmcnt(8)" ::: "memory")
#define VMCNT0  asm volatile("s_waitcnt vmcnt(0)" ::: "memory")
#define LGKM0   asm volatile("s_waitcnt lgkmcnt(0)" ::: "memory")
#define SB0     __builtin_amdgcn_sched_barrier(0)
#define BARRAW  __builtin_amdgcn_s_barrier()

__device__ __forceinline__ unsigned short cvt_bf16(float f) {
  unsigned u = __float_as_uint(f);
  return (unsigned short)((u + 0x7FFFu + ((u >> 16) & 1u)) >> 16);
}

__device__ __forceinline__ void gl_lds16(const void* g, void* l) {
  __builtin_amdgcn_global_load_lds((const __attribute__((address_space(1))) unsigned int*)g,
                                   (__attribute__((address_space(3))) unsigned int*)l, 16, 0, 0);
}

// ---------------- fast path ----------------

// prep: [0,2048) w_in|w_rec transpose + 3-plane i8 split; [2048,2304) w_out
// transpose (bf16); [2304,4352) pack A=[inputs|z] i8 (values exactly 0/1).
__global__ __launch_bounds__(256)
void prep(const float* __restrict__ w_in, const float* __restrict__ w_rec,
          const float* __restrict__ w_out, signed char* __restrict__ Q0,
          signed char* __restrict__ Q1, signed char* __restrict__ Q2,
          short* __restrict__ WoutT,
          const f32x4* __restrict__ ins, const f32x4* __restrict__ zin,
          signed char* __restrict__ Acomb)
{
  __shared__ float tile[64][65];
  const int bx = blockIdx.x, tid = threadIdx.x;
  if (bx >= 2304) {                                      // A pack (exact 0/1)
    const int i = (bx - 2304) * 256 + tid;               // [0, 524288) f32x4
    const f32x4 b = ins[i];
    const f32x4 d = zin[i];
    const int e = i * 4, m = e >> 11, k = e & 2047;
    c8x4 ab, zb;
#pragma unroll
    for (int j = 0; j < 4; ++j) { ab[j] = (char)(b[j] != 0.0f); zb[j] = (char)(d[j] != 0.0f); }
    *(c8x4*)&Acomb[m * 4096 + k] = ab;
    *(c8x4*)&Acomb[m * 4096 + 2048 + k] = zb;
    return;
  }
  const int rr = tid >> 4, c4 = (tid & 15) * 4;
  if (bx < 2048) {                                       // w_in|w_rec, combined k 0..4095
    const int k0 = (bx >> 5) * 64, n0 = (bx & 31) * 64;
#pragma unroll
    for (int p = 0; p < 4; ++p) {
      const int kk = p * 16 + rr, kg = k0 + kk;
      const float* src = (kg < 2048) ? &w_in[kg * 2048 + n0 + c4]
                                     : &w_rec[(kg - 2048) * 2048 + n0 + c4];
      const f32x4 v = *(const f32x4*)src;
#pragma unroll
      for (int j = 0; j < 4; ++j) tile[kk][c4 + j] = v[j];
    }
    __syncthreads();
#pragma unroll
    for (int p = 0; p < 4; ++p) {
      const int nn = p * 16 + rr;
      c8x4 b0, b1, b2;
#pragma unroll
      for (int j = 0; j < 4; ++j) {
        int q = __float2int_rn(tile[c4 + j][nn] * SINVF);
        const int d2 = ((q + 64) & 127) - 64;  q = (q - d2) >> 7;
        const int d1 = ((q + 64) & 127) - 64;  q = (q - d1) >> 7;   // q = digit0
        b2[j] = (char)d2; b1[j] = (char)d1; b0[j] = (char)q;
      }
      const long off = (long)(n0 + nn) * 4096 + k0 + c4;
      *(c8x4*)&Q0[off] = b0;
      *(c8x4*)&Q1[off] = b1;
      *(c8x4*)&Q2[off] = b2;
    }
  } else {                                               // w_out [2048][512] -> WoutT bf16
    const int b2 = bx - 2048;
    const int k0 = (b2 >> 3) * 64, n0 = (b2 & 7) * 64;
#pragma unroll
    for (int p = 0; p < 4; ++p) {
      const int kk = p * 16 + rr;
      const f32x4 v = *(const f32x4*)&w_out[(k0 + kk) * 512 + n0 + c4];
#pragma unroll
      for (int j = 0; j < 4; ++j) tile[kk][c4 + j] = v[j];
    }
    __syncthreads();
#pragma unroll
    for (int p = 0; p < 4; ++p) {
      const int nn = p * 16 + rr;
      s16x4 hh;
#pragma unroll
      for (int j = 0; j < 4; ++j) hh[j] = (short)cvt_bf16(tile[c4 + j][nn]);
      *(s16x4*)&WoutT[(n0 + nn) * 2048 + k0 + c4] = hh;
    }
  }
}

// gemm1: exact-i8 3-plane, 128x128 tile, K-split 2 (K=2048 each, KT=16 steps of
//   128), grid 256 (1/CU, ONE pass), 512 thr / 8 waves, wave tile 64x32
//   (2M x 4N: the 3-plane B is replicated only 2x, cheap A 4x -> LDS read/kt
//   drops 224->160 KB vs R14's 4M x 2N; acc = 4x2x3 = 24 i32x4, no spill).
//   R8-proven 128-B rows + ts^(r&7) involution (measured 0 bank conflicts).
//   T3/T4 depth-2 pipeline: LDS ping-pong 2x64KB, counted vmcnt(8).
__global__ __launch_bounds__(512, 1)
void gemm1(const signed char* __restrict__ Ag, const signed char* __restrict__ Q0g,
           const signed char* __restrict__ Q1g, const signed char* __restrict__ Q2g,
           int* __restrict__ outp)
{
  constexpr int KT = 16;
  __shared__ __align__(16) signed char L[2][4][16384];   // [buf][A,Q0,Q1,Q2]

  const int tid = threadIdx.x, lane = tid & 63, wv = tid >> 6;   // 8 waves
  const int lr = lane & 15, hl = lane >> 4;
  const int r8 = lane >> 3, ts = lane & 7;

  // XCD-chunked swizzle (256 % 8 == 0)
  const int bid = blockIdx.x;
  const int swz = (bid & 7) * 32 + (bid >> 3);
  const int m0 = (swz & 7) * 128;
  const int n0 = ((swz >> 3) & 15) * 128;
  const int kz = swz >> 7;                               // 2 K-halves
  const int kb = kz * 2048;
  int* P = outp + (size_t)kz * (Bq * Hq);

  const int wm = (wv & 1) * 64;          // 2 M-groups (A replicated 4x)
  const int wn = (wv >> 1) * 32;         // 4 N-groups (3-plane B replicated 2x)

  i32x4 a0[4][2], a1[4][2], a2[4][2];
#pragma unroll
  for (int mi = 0; mi < 4; ++mi)
#pragma unroll
    for (int ni = 0; ni < 2; ++ni) {
      a0[mi][ni] = (i32x4){0, 0, 0, 0};
      a1[mi][ni] = (i32x4){0, 0, 0, 0};
      a2[mi][ni] = (i32x4){0, 0, 0, 0};
    }

  // global source pre-swizzled (16B chunks XOR row&7); LDS dest linear (G21).
  // 8 gl_lds per wave per STAGE -> steady-state vmcnt(8) = current buf ready.
  auto STAGE = [&](int kt, int c) {
    const int k = kb + kt * 128;
#pragma unroll
    for (int q = 0; q < 2; ++q) {
      const int slot = wv * 2 + q;              // 0..15
      const int r = slot * 8 + r8;              // 0..127
      const int s = ts ^ (r & 7);
      const size_t go = (size_t)r * 4096 + k + s * 16;
      gl_lds16(Ag  + (size_t)m0 * 4096 + go, &L[c][0][slot * 1024]);
      gl_lds16(Q0g + (size_t)n0 * 4096 + go, &L[c][1][slot * 1024]);
      gl_lds16(Q1g + (size_t)n0 * 4096 + go, &L[c][2][slot * 1024]);
      gl_lds16(Q2g + (size_t)n0 * 4096 + go, &L[c][3][slot * 1024]);
    }
  };

  auto COMPUTE = [&](int c) {
#pragma unroll
    for (int ks = 0; ks < 2; ++ks) {
      i32x4 af[4];
#pragma unroll
      for (int mi = 0; mi < 4; ++mi) {
        const int ar = wm + mi * 16 + lr;
        af[mi] = *(const i32x4*)&L[c][0][ar * 128 + (((ks * 4 + hl) ^ (ar & 7)) << 4)];
      }
#pragma unroll
      for (int ni = 0; ni < 2; ++ni) {
        const int br = wn + ni * 16 + lr;
        const int sp = br * 128 + (((ks * 4 + hl) ^ (br & 7)) << 4);
        const i32x4 b0 = *(const i32x4*)&L[c][1][sp];
#pragma unroll
        for (int mi = 0; mi < 4; ++mi)
          a0[mi][ni] = __builtin_amdgcn_mfma_i32_16x16x64_i8(af[mi], b0, a0[mi][ni], 0, 0, 0);
        const i32x4 b1 = *(const i32x4*)&L[c][2][sp];
#pragma unroll
        for (int mi = 0; mi < 4; ++mi)
          a1[mi][ni] = __builtin_amdgcn_mfma_i32_16x16x64_i8(af[mi], b1, a1[mi][ni], 0, 0, 0);
        const i32x4 b2 = *(const i32x4*)&L[c][3][sp];
#pragma unroll
        for (int mi = 0; mi < 4; ++mi)
          a2[mi][ni] = __builtin_amdgcn_mfma_i32_16x16x64_i8(af[mi], b2, a2[mi][ni], 0, 0, 0);
      }
    }
  };

  STAGE(0, 0);
  STAGE(1, 1);
  for (int kt = 0; kt < KT - 1; ++kt) {
    VMCNT8; SB0; BARRAW; SB0;          // own 8 oldest done + all waves past wait
    COMPUTE(kt & 1);
    LGKM0; SB0; BARRAW; SB0;           // all reads of this buf done everywhere
    if (kt + 2 < KT) STAGE(kt + 2, kt & 1);
  }
  VMCNT0; SB0; BARRAW; SB0;            // final tile: drain
  COMPUTE((KT - 1) & 1);

  // C/D frag layout col=lane&15, row=(lane>>4)*4+reg (dtype-independent)
#pragma unroll
  for (int mi = 0; mi < 4; ++mi)
#pragma unroll
    for (int ni = 0; ni < 2; ++ni)
#pragma unroll
      for (int j = 0; j < 4; ++j) {
        const int m = m0 + wm + mi * 16 + hl * 4 + j;
        const int n = n0 + wn + ni * 16 + lr;
        P[m * Hq + n] = (a0[mi][ni][j] << 14) + (a1[mi][ni][j] << 7) + a2[mi][ni][j];
      }
}

// combine 2 i32 partials (exact, fixed order) + LIF elementwise; emit new_z bf16
__global__ __launch_bounds__(256)
void lif_epi(const i32x4* __restrict__ Pp, const f32x4* __restrict__ vin,
             const f32x4* __restrict__ zin, const f32x4* __restrict__ rin,
             float* __restrict__ dout, short* __restrict__ z2)
{
  const int i = blockIdx.x * 256 + threadIdx.x;          // 2048 blocks x 256 = exact
  const i32x4 c = Pp[i] + Pp[i + 524288];
  const double S = 1.0 / (double)SINVF;
  const f32x4 vo = vin[i], zo = zin[i], ro = rin[i];
  f32x4 nv, nz, nr, dz;
  s16x4 zb;
#pragma unroll
  for (int j = 0; j < 4; ++j) {
    const float it = (float)((double)c[j] * S);
    const float v1 = DECAYF * vo[j] + it - zo[j] * THRF;
    const float vs = (v1 - THRF) / THRF;
    const bool refr = ro[j] > 0.1f;
    const float z1 = (refr || !(vs > 0.0f)) ? 0.0f : 1.0f;
    nv[j] = v1; nz[j] = z1;
    nr[j] = fminf(fmaxf(ro[j] + 5.0f * z1 - 1.0f, 0.0f), 5.0f);
    dz[j] = refr ? 0.0f : (fmaxf(0.3f * (1.0f - fabsf(vs)), 0.0f) / THRF);
    zb[j] = (short)cvt_bf16(z1);
  }
  ((f32x4*)(dout + OFF_V))[i] = nv;
  ((f32x4*)(dout + OFF_Z))[i] = nz;
  ((f32x4*)(dout + OFF_R))[i] = nr;
  ((f32x4*)(dout + OFF_DZ))[i] = dz;
  ((s16x4*)z2)[i] = zb;
}

// tail: blocks [0,256) gemm2 (new_out = kappa*out + Z2 @ WoutT, 32x64 tile, bf16);
//       blocks [256,2304) trace filters (overlap the latency-bound gemm2).
__global__ __launch_bounds__(256)
void tail(const short* __restrict__ Ag, const short* __restrict__ Whg,
          const float* __restrict__ e0, float* __restrict__ outp,
          const f32x4* __restrict__ tin, const f32x4* __restrict__ ins,
          const f32x4* __restrict__ trec, const f32x4* __restrict__ zin,
          f32x4* __restrict__ o1, f32x4* __restrict__ o2)
{
  constexpr int BM = 32, BN = 64, MR = 1, NR = 2, KT = 32, AK = 2048;
  constexpr int APW = BM / 32, WPW = BN / 32;
  __shared__ __align__(16) short As[BM * 64];
  __shared__ __align__(16) short Wh[BN * 64];

  const int bid = blockIdx.x, tid = threadIdx.x;
  if (bid >= 256) {                                      // trace filters
    const int i = (bid - 256) * 256 + tid;               // [0, 524288) f32x4
    o1[i] = tin[i] * DECAYF + ins[i];
    o2[i] = trec[i] * DECAYF + zin[i];
    return;
  }
  const int lane = tid & 63, wv = tid >> 6;
  const int lr = lane & 15, hl = lane >> 4;
  const int rA = lane >> 3, ts = lane & 7;
  const int m0 = (bid >> 3) * BM, n0 = (bid & 7) * BN;
  const int wm = (wv >> 1) * (MR * 16);
  const int wn = (wv & 1) * (NR * 16);

  f32x4 acc[MR][NR];
#pragma unroll
  for (int mi = 0; mi < MR; ++mi)
#pragma unroll
    for (int ni = 0; ni < NR; ++ni) acc[mi][ni] = (f32x4){0.f, 0.f, 0.f, 0.f};

  auto STAGE = [&](int kt) {
    const int k = kt * 64;
#pragma unroll
    for (int q = 0; q < APW; ++q) {
      const int slot = wv * APW + q;
      const int r = slot * 8 + rA;
      const int s = ts ^ (r & 7);
      gl_lds16(Ag + (m0 + r) * AK + k + s * 8, &As[slot * 512]);
    }
#pragma unroll
    for (int q = 0; q < WPW; ++q) {
      const int slot = wv * WPW + q;
      const int r = slot * 8 + rA;
      const int s = ts ^ (r & 7);
      gl_lds16(Whg + (n0 + r) * AK + k + s * 8, &Wh[slot * 512]);
    }
  };

  STAGE(0);
  for (int kt = 0; kt < KT; ++kt) {
    __syncthreads();
#pragma unroll
    for (int ks = 0; ks < 2; ++ks) {
      bf16x8 af[MR];
#pragma unroll
      for (int mi = 0; mi < MR; ++mi) {
        const int r = wm + mi * 16 + lr;
        af[mi] = *(const bf16x8*)&As[r * 64 + (((ks * 4 + hl) ^ (r & 7)) << 3)];
      }
#pragma unroll
      for (int ni = 0; ni < NR; ++ni) {
        const int rn = wn + ni * 16 + lr;
        const int sp = (((ks * 4 + hl) ^ (rn & 7)) << 3);
        const bf16x8 bh = *(const bf16x8*)&Wh[rn * 64 + sp];
#pragma unroll
        for (int mi = 0; mi < MR; ++mi)
          acc[mi][ni] = __builtin_amdgcn_mfma_f32_16x16x32_bf16(af[mi], bh, acc[mi][ni], 0, 0, 0);
      }
    }
    __syncthreads();
    if (kt + 1 < KT) STAGE(kt + 1);
  }

#pragma unroll
  for (int mi = 0; mi < MR; ++mi)
#pragma unroll
    for (int ni = 0; ni < NR; ++ni)
#pragma unroll
      for (int j = 0; j < 4; ++j) {
        const int m = m0 + wm + mi * 16 + hl * 4 + j;
        const int n = n0 + wn + ni * 16 + lr;
        const int idx = m * NOUTq + n;
        outp[idx] = DECAYF * e0[idx] + acc[mi][ni][j];
      }
}

// ---------------- fallback path (round-1, used if ws too small) ----------------

template<int MODE>
__global__ __launch_bounds__(256, 1)
void fb_gemm(const float* __restrict__ A0g, const float* __restrict__ A1g,
             const float* __restrict__ W0g, const float* __restrict__ W1g,
             const float* __restrict__ e0, const float* __restrict__ e1,
             const float* __restrict__ e2, float* __restrict__ dout)
{
  constexpr int BM = (MODE == 0) ? 64 : 32;
  constexpr int BN = (MODE == 0) ? 128 : 64;
  constexpr int BK = 64;
  constexpr int LDA = BK + 8;
  constexpr int MR = (MODE == 0) ? 2 : 1;
  constexpr int NR = (MODE == 0) ? 4 : 2;
  constexpr int WM = MR * 16, WN = NR * 16;
  constexpr int KT = (MODE == 0) ? 64 : 32;
  constexpr int Nmat = (MODE == 0) ? Hq : NOUTq;
  constexpr int QA = BM / 16;
  constexpr int QW = (16 * BN) / 256;
  constexpr int KSH = (MODE == 0) ? 7 : 6;
  constexpr int KSTEP = (MODE == 0) ? 2 : 4;

  __shared__ __align__(16) short As[BM * LDA];
  __shared__ __align__(16) short Wh[BN * LDA];
  __shared__ __align__(16) short Wl[((MODE == 0) ? BN : 1) * LDA];

  const int tid  = threadIdx.x;
  const int lane = tid & 63;
  const int wave = tid >> 6;
  const int lr = lane & 15, hl = lane >> 4;
  const int wmOff = (wave >> 1) * WM;
  const int wnOff = (wave & 1) * WN;
  const int m0 = blockIdx.y * BM;
  const int n0 = blockIdx.x * BN;
  const int arow = tid >> 4, ac4 = tid & 15;
  const int wn = tid & (BN - 1);

  f32x4 aR[QA];
  float wR[QW][4];
  f32x4 acc[MR][NR];
#pragma unroll
  for (int mi = 0; mi < MR; ++mi)
#pragma unroll
    for (int ni = 0; ni < NR; ++ni)
      acc[mi][ni] = (f32x4){0.f, 0.f, 0.f, 0.f};

  auto LOAD = [&](int kt) {
    const float* Ag = A0g; const float* Wg = W0g; int k0 = kt * BK;
    if (MODE == 0 && kt >= 32) { Ag = A1g; Wg = W1g; k0 = (kt - 32) * BK; }
#pragma unroll
    for (int q = 0; q < QA; ++q)
      aR[q] = *(const f32x4*)&Ag[(m0 + arow + q * 16) * 2048 + k0 + ac4 * 4];
#pragma unroll
    for (int p = 0; p < QW; ++p) {
      const int kq = (tid >> KSH) + p * KSTEP;
#pragma unroll
      for (int i = 0; i < 4; ++i)
        wR[p][i] = Wg[(k0 + kq * 4 + i) * Nmat + n0 + wn];
    }
  };

  auto STORE = [&]() {
#pragma unroll
    for (int q = 0; q < QA; ++q) {
      s16x4 hv;
#pragma unroll
      for (int j = 0; j < 4; ++j) hv[j] = (short)cvt_bf16(aR[q][j]);
      *(s16x4*)&As[(arow + q * 16) * LDA + ac4 * 4] = hv;
    }
#pragma unroll
    for (int p = 0; p < QW; ++p) {
      const int kq = (tid >> KSH) + p * KSTEP;
      s16x4 hh, ll;
#pragma unroll
      for (int i = 0; i < 4; ++i) {
        const float w = wR[p][i];
        const unsigned short h = cvt_bf16(w);
        hh[i] = (short)h;
        if (MODE == 0) {
          const float hf = __uint_as_float(((unsigned)h) << 16);
          ll[i] = (short)cvt_bf16(w - hf);
        }
      }
      *(s16x4*)&Wh[wn * LDA + kq * 4] = hh;
      if (MODE == 0) *(s16x4*)&Wl[wn * LDA + kq * 4] = ll;
    }
  };

  LOAD(0);
  for (int kt = 0; kt < KT; ++kt) {
    __syncthreads();
    STORE();
    __syncthreads();
    if (kt + 1 < KT) LOAD(kt + 1);
#pragma unroll
    for (int ks = 0; ks < 2; ++ks) {
      bf16x8 af[MR];
#pragma unroll
      for (int mi = 0; mi < MR; ++mi)
        af[mi] = *(const bf16x8*)&As[(wmOff + mi * 16 + lr) * LDA + ks * 32 + hl * 8];
#pragma unroll
      for (int ni = 0; ni < NR; ++ni) {
        const bf16x8 bh = *(const bf16x8*)&Wh[(wnOff + ni * 16 + lr) * LDA + ks * 32 + hl * 8];
#pragma unroll
        for (int mi = 0; mi < MR; ++mi)
          acc[mi][ni] = __builtin_amdgcn_mfma_f32_16x16x32_bf16(af[mi], bh, acc[mi][ni], 0, 0, 0);
        if (MODE == 0) {
          const bf16x8 bl = *(const bf16x8*)&Wl[(wnOff + ni * 16 + lr) * LDA + ks * 32 + hl * 8];
#pragma unroll
          for (int mi = 0; mi < MR; ++mi)
            acc[mi][ni] = __builtin_amdgcn_mfma_f32_16x16x32_bf16(af[mi], bl, acc[mi][ni], 0, 0, 0);
        }
      }
    }
  }

#pragma unroll
  for (int mi = 0; mi < MR; ++mi) {
#pragma unroll
    for (int ni = 0; ni < NR; ++ni) {
#pragma unroll
      for (int j = 0; j < 4; ++j) {
        const int m = m0 + wmOff + mi * 16 + hl * 4 + j;
        const int n = n0 + wnOff + ni * 16 + lr;
        if (MODE == 0) {
          const int idx = m * Hq + n;
          const float it = acc[mi][ni][j];
          const float vold = e0[idx];
          const float zold = e1[idx];
          const float rold = e2[idx];
          const float nv = DECAYF * vold + it - zold * THRF;
          const float vs = (nv - THRF) / THRF;
          const bool refr = rold > 0.1f;
          const float nz = (refr || !(vs > 0.0f)) ? 0.0f : 1.0f;
          const float nr = fminf(fmaxf(rold + 5.0f * nz - 1.0f, 0.0f), 5.0f);
          const float dz = refr ? 0.0f : (fmaxf(0.3f * (1.0f - fabsf(vs)), 0.0f) / THRF);
          dout[OFF_V + idx] = nv;
          dout[OFF_Z + idx] = nz;
          dout[OFF_R + idx] = nr;
          dout[OFF_DZ + idx] = dz;
        } else {
          const int idx = m * NOUTq + n;
          dout[OFF_OUT + idx] = DECAYF * e0[idx] + acc[mi][ni][j];
        }
      }
    }
  }
}

__global__ __launch_bounds__(256)
void fb_trace(const float4* __restrict__ tin, const float4* __restrict__ ins,
              const float4* __restrict__ trec, const float4* __restrict__ zin,
              float4* __restrict__ o1, float4* __restrict__ o2)
{
  const int n4 = (Bq * 2048) / 4;
  for (int i = blockIdx.x * blockDim.x + threadIdx.x; i < n4; i += gridDim.x * blockDim.x) {
    const float4 a = tin[i], b = ins[i];
    float4 u;
    u.x = a.x * DECAYF + b.x; u.y = a.y * DECAYF + b.y;
    u.z = a.z * DECAYF + b.z; u.w = a.w * DECAYF + b.w;
    o1[i] = u;
    const float4 c = trec[i], d = zin[i];
    float4 w;
    w.x = c.x * DECAYF + d.x; w.y = c.y * DECAYF + d.y;
    w.z = c.z * DECAYF + d.z; w.w = c.w * DECAYF + d.w;
    o2[i] = w;
  }
}

extern "C" void kernel_launch(void* const* d_in, const int* in_sizes, int n_in,
                              void* d_out, int out_size, void* d_ws, size_t ws_size,
                              hipStream_t stream) {
  const float* inputs = (const float*)d_in[0];
  const float* v      = (const float*)d_in[1];
  const float* z      = (const float*)d_in[2];
  const float* r      = (const float*)d_in[3];
  const float* outp   = (const float*)d_in[4];
  const float* tin    = (const float*)d_in[5];
  const float* trec   = (const float*)d_in[6];
  const float* w_in   = (const float*)d_in[7];
  const float* w_rec  = (const float*)d_in[8];
  const float* w_out  = (const float*)d_in[9];
  float* out = (float*)d_out;

  if (ws_size >= WS_NEED) {
    char* ws = (char*)d_ws;
    signed char* A  = (signed char*)(ws + WS_A);
    signed char* Q0 = (signed char*)(ws + WS_Q0);
    signed char* Q1 = (signed char*)(ws + WS_Q1);
    signed char* Q2 = (signed char*)(ws + WS_Q2);
    short* WoutT    = (short*)(ws + WS_WOUTT);
    int* P          = (int*)(ws + WS_P);
    short* Z2       = (short*)(ws + WS_Z2);

    prep<<<4352, 256, 0, stream>>>(w_in, w_rec, w_out, Q0, Q1, Q2, WoutT,
                                   (const f32x4*)inputs, (const f32x4*)z, A);
    gemm1<<<256, 512, 0, stream>>>(A, Q0, Q1, Q2, P);
    lif_epi<<<2048, 256, 0, stream>>>((const i32x4*)P, (const f32x4*)v, (const f32x4*)z,
                                      (const f32x4*)r, out, Z2);
    tail<<<2304, 256, 0, stream>>>(Z2, WoutT, outp, out + OFF_OUT,
                                   (const f32x4*)tin, (const f32x4*)inputs,
                                   (const f32x4*)trec, (const f32x4*)z,
                                   (f32x4*)(out + OFF_TIN), (f32x4*)(out + OFF_TREC));
  } else {
    fb_trace<<<2048, 256, 0, stream>>>((const float4*)tin, (const float4*)inputs,
                                       (const float4*)trec, (const float4*)z,
                                       (float4*)(out + OFF_TIN), (float4*)(out + OFF_TREC));
    fb_gemm<0><<<dim3(16, 16), 256, 0, stream>>>(inputs, z, w_in, w_rec, v, z, r, out);
    fb_gemm<1><<<dim3(8, 32), 256, 0, stream>>>(out + OFF_Z, nullptr, w_out, nullptr,
                                                outp, nullptr, nullptr, out);
  }
}

// Round 16
// 81.335 us; speedup vs baseline: 1.0129x; 1.0129x over previous
//
#include <hip/hip_runtime.h>

#define Bq 1024
#define Hq 2048
#define NOUTq 512

#define DECAYF 0.95122942450071400910f
#define THRF 0.4f
#define SINVF 5931641.0f            // 2^22.5-ish; |q| <= ~712K, digits fit i8

// d_out offsets (in floats), outputs concatenated in return order
#define OFF_OUT  0
#define OFF_Z    524288
#define OFF_V    2621440
#define OFF_R    4718592
#define OFF_TIN  6815744
#define OFF_TREC 8912896
#define OFF_DZ   11010048

// ws layout (bytes)
#define WS_A     0ul           // i8 [1024][4096]  (inputs | z)          4 MB
#define WS_Q0    4194304ul     // i8 W^T plane0 [2048][4096]             8 MB
#define WS_Q1    12582912ul    // i8 W^T plane1                          8 MB
#define WS_Q2    20971520ul    // i8 W^T plane2                          8 MB
#define WS_WOUTT 29360128ul    // bf16 w_out^T [512][2048]               2 MB
#define WS_P     31457280ul    // i32 partials [2][1024][2048] (16 MB used)
#define WS_Z2    65011712ul    // bf16 new_z [1024][2048]                4 MB
#define WS_NEED  69206016ul

typedef __attribute__((ext_vector_type(8))) short  bf16x8;
typedef __attribute__((ext_vector_type(4))) short  s16x4;
typedef __attribute__((ext_vector_type(4))) float  f32x4;
typedef __attribute__((ext_vector_type(4))) int    i32x4;
typedef __attribute__((ext_vector_type(4))) char   c8x4;

// T3/T4 pipeline fences (rule #18: memory clobber + sched_barrier around waits)
#define VMCNT8  asm volatile("s_waitcnt vmcnt(8)" ::: "memory")
#define VMCNT0  asm volatile("s_waitcnt vmcnt(0)" ::: "memory")
#define LGKM0   asm volatile("s_waitcnt lgkmcnt(0)" ::: "memory")
#define SB0     __builtin_amdgcn_sched_barrier(0)
#define BARRAW  __builtin_amdgcn_s_barrier()

__device__ __forceinline__ unsigned short cvt_bf16(float f) {
  unsigned u = __float_as_uint(f);
  return (unsigned short)((u + 0x7FFFu + ((u >> 16) & 1u)) >> 16);
}

__device__ __forceinline__ void gl_lds16(const void* g, void* l) {
  __builtin_amdgcn_global_load_lds((const __attribute__((address_space(1))) unsigned int*)g,
                                   (__attribute__((address_space(3))) unsigned int*)l, 16, 0, 0);
}

// ---------------- fast path ----------------

// prep: [0,2048) w_in|w_rec transpose + 3-plane i8 split; [2048,2304) w_out
// transpose (bf16); [2304,4352) pack A=[inputs|z] i8 (values exactly 0/1).
__global__ __launch_bounds__(256)
void prep(const float* __restrict__ w_in, const float* __restrict__ w_rec,
          const float* __restrict__ w_out, signed char* __restrict__ Q0,
          signed char* __restrict__ Q1, signed char* __restrict__ Q2,
          short* __restrict__ WoutT,
          const f32x4* __restrict__ ins, const f32x4* __restrict__ zin,
          signed char* __restrict__ Acomb)
{
  __shared__ float tile[64][65];
  const int bx = blockIdx.x, tid = threadIdx.x;
  if (bx >= 2304) {                                      // A pack (exact 0/1)
    const int i = (bx - 2304) * 256 + tid;               // [0, 524288) f32x4
    const f32x4 b = ins[i];
    const f32x4 d = zin[i];
    const int e = i * 4, m = e >> 11, k = e & 2047;
    c8x4 ab, zb;
#pragma unroll
    for (int j = 0; j < 4; ++j) { ab[j] = (char)(b[j] != 0.0f); zb[j] = (char)(d[j] != 0.0f); }
    *(c8x4*)&Acomb[m * 4096 + k] = ab;
    *(c8x4*)&Acomb[m * 4096 + 2048 + k] = zb;
    return;
  }
  const int rr = tid >> 4, c4 = (tid & 15) * 4;
  if (bx < 2048) {                                       // w_in|w_rec, combined k 0..4095
    const int k0 = (bx >> 5) * 64, n0 = (bx & 31) * 64;
#pragma unroll
    for (int p = 0; p < 4; ++p) {
      const int kk = p * 16 + rr, kg = k0 + kk;
      const float* src = (kg < 2048) ? &w_in[kg * 2048 + n0 + c4]
                                     : &w_rec[(kg - 2048) * 2048 + n0 + c4];
      const f32x4 v = *(const f32x4*)src;
#pragma unroll
      for (int j = 0; j < 4; ++j) tile[kk][c4 + j] = v[j];
    }
    __syncthreads();
#pragma unroll
    for (int p = 0; p < 4; ++p) {
      const int nn = p * 16 + rr;
      c8x4 b0, b1, b2;
#pragma unroll
      for (int j = 0; j < 4; ++j) {
        int q = __float2int_rn(tile[c4 + j][nn] * SINVF);
        const int d2 = ((q + 64) & 127) - 64;  q = (q - d2) >> 7;
        const int d1 = ((q + 64) & 127) - 64;  q = (q - d1) >> 7;   // q = digit0
        b2[j] = (char)d2; b1[j] = (char)d1; b0[j] = (char)q;
      }
      const long off = (long)(n0 + nn) * 4096 + k0 + c4;
      *(c8x4*)&Q0[off] = b0;
      *(c8x4*)&Q1[off] = b1;
      *(c8x4*)&Q2[off] = b2;
    }
  } else {                                               // w_out [2048][512] -> WoutT bf16
    const int b2 = bx - 2048;
    const int k0 = (b2 >> 3) * 64, n0 = (b2 & 7) * 64;
#pragma unroll
    for (int p = 0; p < 4; ++p) {
      const int kk = p * 16 + rr;
      const f32x4 v = *(const f32x4*)&w_out[(k0 + kk) * 512 + n0 + c4];
#pragma unroll
      for (int j = 0; j < 4; ++j) tile[kk][c4 + j] = v[j];
    }
    __syncthreads();
#pragma unroll
    for (int p = 0; p < 4; ++p) {
      const int nn = p * 16 + rr;
      s16x4 hh;
#pragma unroll
      for (int j = 0; j < 4; ++j) hh[j] = (short)cvt_bf16(tile[c4 + j][nn]);
      *(s16x4*)&WoutT[(n0 + nn) * 2048 + k0 + c4] = hh;
    }
  }
}

// gemm1: exact-i8 3-plane, 128x128 tile, K-split 2 (K=2048 each, KT=16 steps of
//   128), grid 256 (1/CU, ONE pass), 512 thr / 8 waves, wave tile 32x64
//   (4M x 2N; acc = 2x4x3 = 24 i32x4 -> no spill; R14 measured-best config).
//   R8-proven 128-B rows + ts^(r&7) involution (measured 0 bank conflicts).
//   T3/T4 depth-2 pipeline: LDS ping-pong 2x64KB, counted vmcnt(8).
//   Ceiling note: staging-rate invariant ~7.5 TB/s aggregate over R7-R15 -> this
//   config's ~34 us is its structural floor; wave/tile reshapes are neutral.
__global__ __launch_bounds__(512, 1)
void gemm1(const signed char* __restrict__ Ag, const signed char* __restrict__ Q0g,
           const signed char* __restrict__ Q1g, const signed char* __restrict__ Q2g,
           int* __restrict__ outp)
{
  constexpr int KT = 16;
  __shared__ __align__(16) signed char L[2][4][16384];   // [buf][A,Q0,Q1,Q2]

  const int tid = threadIdx.x, lane = tid & 63, wv = tid >> 6;   // 8 waves
  const int lr = lane & 15, hl = lane >> 4;
  const int r8 = lane >> 3, ts = lane & 7;

  // XCD-chunked swizzle (256 % 8 == 0)
  const int bid = blockIdx.x;
  const int swz = (bid & 7) * 32 + (bid >> 3);
  const int m0 = (swz & 7) * 128;
  const int n0 = ((swz >> 3) & 15) * 128;
  const int kz = swz >> 7;                               // 2 K-halves
  const int kb = kz * 2048;
  int* P = outp + (size_t)kz * (Bq * Hq);

  const int wm = (wv & 3) * 32;          // 4 M-groups
  const int wn = (wv >> 2) * 64;         // 2 N-groups

  i32x4 a0[2][4], a1[2][4], a2[2][4];
#pragma unroll
  for (int mi = 0; mi < 2; ++mi)
#pragma unroll
    for (int ni = 0; ni < 4; ++ni) {
      a0[mi][ni] = (i32x4){0, 0, 0, 0};
      a1[mi][ni] = (i32x4){0, 0, 0, 0};
      a2[mi][ni] = (i32x4){0, 0, 0, 0};
    }

  // global source pre-swizzled (16B chunks XOR row&7); LDS dest linear (G21).
  // 8 gl_lds per wave per STAGE -> steady-state vmcnt(8) = current buf ready.
  auto STAGE = [&](int kt, int c) {
    const int k = kb + kt * 128;
#pragma unroll
    for (int q = 0; q < 2; ++q) {
      const int slot = wv * 2 + q;              // 0..15
      const int r = slot * 8 + r8;              // 0..127
      const int s = ts ^ (r & 7);
      const size_t go = (size_t)r * 4096 + k + s * 16;
      gl_lds16(Ag  + (size_t)m0 * 4096 + go, &L[c][0][slot * 1024]);
      gl_lds16(Q0g + (size_t)n0 * 4096 + go, &L[c][1][slot * 1024]);
      gl_lds16(Q1g + (size_t)n0 * 4096 + go, &L[c][2][slot * 1024]);
      gl_lds16(Q2g + (size_t)n0 * 4096 + go, &L[c][3][slot * 1024]);
    }
  };

  auto COMPUTE = [&](int c) {
#pragma unroll
    for (int ks = 0; ks < 2; ++ks) {
      i32x4 af[2];
#pragma unroll
      for (int mi = 0; mi < 2; ++mi) {
        const int ar = wm + mi * 16 + lr;
        af[mi] = *(const i32x4*)&L[c][0][ar * 128 + (((ks * 4 + hl) ^ (ar & 7)) << 4)];
      }
#pragma unroll
      for (int ni = 0; ni < 4; ++ni) {
        const int br = wn + ni * 16 + lr;
        const int sp = br * 128 + (((ks * 4 + hl) ^ (br & 7)) << 4);
        const i32x4 b0 = *(const i32x4*)&L[c][1][sp];
#pragma unroll
        for (int mi = 0; mi < 2; ++mi)
          a0[mi][ni] = __builtin_amdgcn_mfma_i32_16x16x64_i8(af[mi], b0, a0[mi][ni], 0, 0, 0);
        const i32x4 b1 = *(const i32x4*)&L[c][2][sp];
#pragma unroll
        for (int mi = 0; mi < 2; ++mi)
          a1[mi][ni] = __builtin_amdgcn_mfma_i32_16x16x64_i8(af[mi], b1, a1[mi][ni], 0, 0, 0);
        const i32x4 b2 = *(const i32x4*)&L[c][3][sp];
#pragma unroll
        for (int mi = 0; mi < 2; ++mi)
          a2[mi][ni] = __builtin_amdgcn_mfma_i32_16x16x64_i8(af[mi], b2, a2[mi][ni], 0, 0, 0);
      }
    }
  };

  STAGE(0, 0);
  STAGE(1, 1);
  for (int kt = 0; kt < KT - 1; ++kt) {
    VMCNT8; SB0; BARRAW; SB0;          // own 8 oldest done + all waves past wait
    COMPUTE(kt & 1);
    LGKM0; SB0; BARRAW; SB0;           // all reads of this buf done everywhere
    if (kt + 2 < KT) STAGE(kt + 2, kt & 1);
  }
  VMCNT0; SB0; BARRAW; SB0;            // final tile: drain
  COMPUTE((KT - 1) & 1);

  // C/D frag layout col=lane&15, row=(lane>>4)*4+reg (dtype-independent)
#pragma unroll
  for (int mi = 0; mi < 2; ++mi)
#pragma unroll
    for (int ni = 0; ni < 4; ++ni)
#pragma unroll
      for (int j = 0; j < 4; ++j) {
        const int m = m0 + wm + mi * 16 + hl * 4 + j;
        const int n = n0 + wn + ni * 16 + lr;
        P[m * Hq + n] = (a0[mi][ni][j] << 14) + (a1[mi][ni][j] << 7) + a2[mi][ni][j];
      }
}

// combine 2 i32 partials (exact, fixed order) + LIF elementwise; emit new_z bf16
__global__ __launch_bounds__(256)
void lif_epi(const i32x4* __restrict__ Pp, const f32x4* __restrict__ vin,
             const f32x4* __restrict__ zin, const f32x4* __restrict__ rin,
             float* __restrict__ dout, short* __restrict__ z2)
{
  const int i = blockIdx.x * 256 + threadIdx.x;          // 2048 blocks x 256 = exact
  const i32x4 c = Pp[i] + Pp[i + 524288];
  const double S = 1.0 / (double)SINVF;
  const f32x4 vo = vin[i], zo = zin[i], ro = rin[i];
  f32x4 nv, nz, nr, dz;
  s16x4 zb;
#pragma unroll
  for (int j = 0; j < 4; ++j) {
    const float it = (float)((double)c[j] * S);
    const float v1 = DECAYF * vo[j] + it - zo[j] * THRF;
    const float vs = (v1 - THRF) / THRF;
    const bool refr = ro[j] > 0.1f;
    const float z1 = (refr || !(vs > 0.0f)) ? 0.0f : 1.0f;
    nv[j] = v1; nz[j] = z1;
    nr[j] = fminf(fmaxf(ro[j] + 5.0f * z1 - 1.0f, 0.0f), 5.0f);
    dz[j] = refr ? 0.0f : (fmaxf(0.3f * (1.0f - fabsf(vs)), 0.0f) / THRF);
    zb[j] = (short)cvt_bf16(z1);
  }
  ((f32x4*)(dout + OFF_V))[i] = nv;
  ((f32x4*)(dout + OFF_Z))[i] = nz;
  ((f32x4*)(dout + OFF_R))[i] = nr;
  ((f32x4*)(dout + OFF_DZ))[i] = dz;
  ((s16x4*)z2)[i] = zb;
}

// tail: blocks [0,256) gemm2 (new_out = kappa*out + Z2 @ WoutT, 32x64 tile, bf16);
//       blocks [256,2304) trace filters (overlap the latency-bound gemm2).
__global__ __launch_bounds__(256)
void tail(const short* __restrict__ Ag, const short* __restrict__ Whg,
          const float* __restrict__ e0, float* __restrict__ outp,
          const f32x4* __restrict__ tin, const f32x4* __restrict__ ins,
          const f32x4* __restrict__ trec, const f32x4* __restrict__ zin,
          f32x4* __restrict__ o1, f32x4* __restrict__ o2)
{
  constexpr int BM = 32, BN = 64, MR = 1, NR = 2, KT = 32, AK = 2048;
  constexpr int APW = BM / 32, WPW = BN / 32;
  __shared__ __align__(16) short As[BM * 64];
  __shared__ __align__(16) short Wh[BN * 64];

  const int bid = blockIdx.x, tid = threadIdx.x;
  if (bid >= 256) {                                      // trace filters
    const int i = (bid - 256) * 256 + tid;               // [0, 524288) f32x4
    o1[i] = tin[i] * DECAYF + ins[i];
    o2[i] = trec[i] * DECAYF + zin[i];
    return;
  }
  const int lane = tid & 63, wv = tid >> 6;
  const int lr = lane & 15, hl = lane >> 4;
  const int rA = lane >> 3, ts = lane & 7;
  const int m0 = (bid >> 3) * BM, n0 = (bid & 7) * BN;
  const int wm = (wv >> 1) * (MR * 16);
  const int wn = (wv & 1) * (NR * 16);

  f32x4 acc[MR][NR];
#pragma unroll
  for (int mi = 0; mi < MR; ++mi)
#pragma unroll
    for (int ni = 0; ni < NR; ++ni) acc[mi][ni] = (f32x4){0.f, 0.f, 0.f, 0.f};

  auto STAGE = [&](int kt) {
    const int k = kt * 64;
#pragma unroll
    for (int q = 0; q < APW; ++q) {
      const int slot = wv * APW + q;
      const int r = slot * 8 + rA;
      const int s = ts ^ (r & 7);
      gl_lds16(Ag + (m0 + r) * AK + k + s * 8, &As[slot * 512]);
    }
#pragma unroll
    for (int q = 0; q < WPW; ++q) {
      const int slot = wv * WPW + q;
      const int r = slot * 8 + rA;
      const int s = ts ^ (r & 7);
      gl_lds16(Whg + (n0 + r) * AK + k + s * 8, &Wh[slot * 512]);
    }
  };

  STAGE(0);
  for (int kt = 0; kt < KT; ++kt) {
    __syncthreads();
#pragma unroll
    for (int ks = 0; ks < 2; ++ks) {
      bf16x8 af[MR];
#pragma unroll
      for (int mi = 0; mi < MR; ++mi) {
        const int r = wm + mi * 16 + lr;
        af[mi] = *(const bf16x8*)&As[r * 64 + (((ks * 4 + hl) ^ (r & 7)) << 3)];
      }
#pragma unroll
      for (int ni = 0; ni < NR; ++ni) {
        const int rn = wn + ni * 16 + lr;
        const int sp = (((ks * 4 + hl) ^ (rn & 7)) << 3);
        const bf16x8 bh = *(const bf16x8*)&Wh[rn * 64 + sp];
#pragma unroll
        for (int mi = 0; mi < MR; ++mi)
          acc[mi][ni] = __builtin_amdgcn_mfma_f32_16x16x32_bf16(af[mi], bh, acc[mi][ni], 0, 0, 0);
      }
    }
    __syncthreads();
    if (kt + 1 < KT) STAGE(kt + 1);
  }

#pragma unroll
  for (int mi = 0; mi < MR; ++mi)
#pragma unroll
    for (int ni = 0; ni < NR; ++ni)
#pragma unroll
      for (int j = 0; j < 4; ++j) {
        const int m = m0 + wm + mi * 16 + hl * 4 + j;
        const int n = n0 + wn + ni * 16 + lr;
        const int idx = m * NOUTq + n;
        outp[idx] = DECAYF * e0[idx] + acc[mi][ni][j];
      }
}

// ---------------- fallback path (round-1, used if ws too small) ----------------

template<int MODE>
__global__ __launch_bounds__(256, 1)
void fb_gemm(const float* __restrict__ A0g, const float* __restrict__ A1g,
             const float* __restrict__ W0g, const float* __restrict__ W1g,
             const float* __restrict__ e0, const float* __restrict__ e1,
             const float* __restrict__ e2, float* __restrict__ dout)
{
  constexpr int BM = (MODE == 0) ? 64 : 32;
  constexpr int BN = (MODE == 0) ? 128 : 64;
  constexpr int BK = 64;
  constexpr int LDA = BK + 8;
  constexpr int MR = (MODE == 0) ? 2 : 1;
  constexpr int NR = (MODE == 0) ? 4 : 2;
  constexpr int WM = MR * 16, WN = NR * 16;
  constexpr int KT = (MODE == 0) ? 64 : 32;
  constexpr int Nmat = (MODE == 0) ? Hq : NOUTq;
  constexpr int QA = BM / 16;
  constexpr int QW = (16 * BN) / 256;
  constexpr int KSH = (MODE == 0) ? 7 : 6;
  constexpr int KSTEP = (MODE == 0) ? 2 : 4;

  __shared__ __align__(16) short As[BM * LDA];
  __shared__ __align__(16) short Wh[BN * LDA];
  __shared__ __align__(16) short Wl[((MODE == 0) ? BN : 1) * LDA];

  const int tid  = threadIdx.x;
  const int lane = tid & 63;
  const int wave = tid >> 6;
  const int lr = lane & 15, hl = lane >> 4;
  const int wmOff = (wave >> 1) * WM;
  const int wnOff = (wave & 1) * WN;
  const int m0 = blockIdx.y * BM;
  const int n0 = blockIdx.x * BN;
  const int arow = tid >> 4, ac4 = tid & 15;
  const int wn = tid & (BN - 1);

  f32x4 aR[QA];
  float wR[QW][4];
  f32x4 acc[MR][NR];
#pragma unroll
  for (int mi = 0; mi < MR; ++mi)
#pragma unroll
    for (int ni = 0; ni < NR; ++ni)
      acc[mi][ni] = (f32x4){0.f, 0.f, 0.f, 0.f};

  auto LOAD = [&](int kt) {
    const float* Ag = A0g; const float* Wg = W0g; int k0 = kt * BK;
    if (MODE == 0 && kt >= 32) { Ag = A1g; Wg = W1g; k0 = (kt - 32) * BK; }
#pragma unroll
    for (int q = 0; q < QA; ++q)
      aR[q] = *(const f32x4*)&Ag[(m0 + arow + q * 16) * 2048 + k0 + ac4 * 4];
#pragma unroll
    for (int p = 0; p < QW; ++p) {
      const int kq = (tid >> KSH) + p * KSTEP;
#pragma unroll
      for (int i = 0; i < 4; ++i)
        wR[p][i] = Wg[(k0 + kq * 4 + i) * Nmat + n0 + wn];
    }
  };

  auto STORE = [&]() {
#pragma unroll
    for (int q = 0; q < QA; ++q) {
      s16x4 hv;
#pragma unroll
      for (int j = 0; j < 4; ++j) hv[j] = (short)cvt_bf16(aR[q][j]);
      *(s16x4*)&As[(arow + q * 16) * LDA + ac4 * 4] = hv;
    }
#pragma unroll
    for (int p = 0; p < QW; ++p) {
      const int kq = (tid >> KSH) + p * KSTEP;
      s16x4 hh, ll;
#pragma unroll
      for (int i = 0; i < 4; ++i) {
        const float w = wR[p][i];
        const unsigned short h = cvt_bf16(w);
        hh[i] = (short)h;
        if (MODE == 0) {
          const float hf = __uint_as_float(((unsigned)h) << 16);
          ll[i] = (short)cvt_bf16(w - hf);
        }
      }
      *(s16x4*)&Wh[wn * LDA + kq * 4] = hh;
      if (MODE == 0) *(s16x4*)&Wl[wn * LDA + kq * 4] = ll;
    }
  };

  LOAD(0);
  for (int kt = 0; kt < KT; ++kt) {
    __syncthreads();
    STORE();
    __syncthreads();
    if (kt + 1 < KT) LOAD(kt + 1);
#pragma unroll
    for (int ks = 0; ks < 2; ++ks) {
      bf16x8 af[MR];
#pragma unroll
      for (int mi = 0; mi < MR; ++mi)
        af[mi] = *(const bf16x8*)&As[(wmOff + mi * 16 + lr) * LDA + ks * 32 + hl * 8];
#pragma unroll
      for (int ni = 0; ni < NR; ++ni) {
        const bf16x8 bh = *(const bf16x8*)&Wh[(wnOff + ni * 16 + lr) * LDA + ks * 32 + hl * 8];
#pragma unroll
        for (int mi = 0; mi < MR; ++mi)
          acc[mi][ni] = __builtin_amdgcn_mfma_f32_16x16x32_bf16(af[mi], bh, acc[mi][ni], 0, 0, 0);
        if (MODE == 0) {
          const bf16x8 bl = *(const bf16x8*)&Wl[(wnOff + ni * 16 + lr) * LDA + ks * 32 + hl * 8];
#pragma unroll
          for (int mi = 0; mi < MR; ++mi)
            acc[mi][ni] = __builtin_amdgcn_mfma_f32_16x16x32_bf16(af[mi], bl, acc[mi][ni], 0, 0, 0);
        }
      }
    }
  }

#pragma unroll
  for (int mi = 0; mi < MR; ++mi) {
#pragma unroll
    for (int ni = 0; ni < NR; ++ni) {
#pragma unroll
      for (int j = 0; j < 4; ++j) {
        const int m = m0 + wmOff + mi * 16 + hl * 4 + j;
        const int n = n0 + wnOff + ni * 16 + lr;
        if (MODE == 0) {
          const int idx = m * Hq + n;
          const float it = acc[mi][ni][j];
          const float vold = e0[idx];
          const float zold = e1[idx];
          const float rold = e2[idx];
          const float nv = DECAYF * vold + it - zold * THRF;
          const float vs = (nv - THRF) / THRF;
          const bool refr = rold > 0.1f;
          const float nz = (refr || !(vs > 0.0f)) ? 0.0f : 1.0f;
          const float nr = fminf(fmaxf(rold + 5.0f * nz - 1.0f, 0.0f), 5.0f);
          const float dz = refr ? 0.0f : (fmaxf(0.3f * (1.0f - fabsf(vs)), 0.0f) / THRF);
          dout[OFF_V + idx] = nv;
          dout[OFF_Z + idx] = nz;
          dout[OFF_R + idx] = nr;
          dout[OFF_DZ + idx] = dz;
        } else {
          const int idx = m * NOUTq + n;
          dout[OFF_OUT + idx] = DECAYF * e0[idx] + acc[mi][ni][j];
        }
      }
    }
  }
}

__global__ __launch_bounds__(256)
void fb_trace(const float4* __restrict__ tin, const float4* __restrict__ ins,
              const float4* __restrict__ trec, const float4* __restrict__ zin,
              float4* __restrict__ o1, float4* __restrict__ o2)
{
  const int n4 = (Bq * 2048) / 4;
  for (int i = blockIdx.x * blockDim.x + threadIdx.x; i < n4; i += gridDim.x * blockDim.x) {
    const float4 a = tin[i], b = ins[i];
    float4 u;
    u.x = a.x * DECAYF + b.x; u.y = a.y * DECAYF + b.y;
    u.z = a.z * DECAYF + b.z; u.w = a.w * DECAYF + b.w;
    o1[i] = u;
    const float4 c = trec[i], d = zin[i];
    float4 w;
    w.x = c.x * DECAYF + d.x; w.y = c.y * DECAYF + d.y;
    w.z = c.z * DECAYF + d.z; w.w = c.w * DECAYF + d.w;
    o2[i] = w;
  }
}

extern "C" void kernel_launch(void* const* d_in, const int* in_sizes, int n_in,
                              void* d_out, int out_size, void* d_ws, size_t ws_size,
                              hipStream_t stream) {
  const float* inputs = (const float*)d_in[0];
  const float* v      = (const float*)d_in[1];
  const float* z      = (const float*)d_in[2];
  const float* r      = (const float*)d_in[3];
  const float* outp   = (const float*)d_in[4];
  const float* tin    = (const float*)d_in[5];
  const float* trec   = (const float*)d_in[6];
  const float* w_in   = (const float*)d_in[7];
  const float* w_rec  = (const float*)d_in[8];
  const float* w_out  = (const float*)d_in[9];
  float* out = (float*)d_out;

  if (ws_size >= WS_NEED) {
    char* ws = (char*)d_ws;
    signed char* A  = (signed char*)(ws + WS_A);
    signed char* Q0 = (signed char*)(ws + WS_Q0);
    signed char* Q1 = (signed char*)(ws + WS_Q1);
    signed char* Q2 = (signed char*)(ws + WS_Q2);
    short* WoutT    = (short*)(ws + WS_WOUTT);
    int* P          = (int*)(ws + WS_P);
    short* Z2       = (short*)(ws + WS_Z2);

    prep<<<4352, 256, 0, stream>>>(w_in, w_rec, w_out, Q0, Q1, Q2, WoutT,
                                   (const f32x4*)inputs, (const f32x4*)z, A);
    gemm1<<<256, 512, 0, stream>>>(A, Q0, Q1, Q2, P);
    lif_epi<<<2048, 256, 0, stream>>>((const i32x4*)P, (const f32x4*)v, (const f32x4*)z,
                                      (const f32x4*)r, out, Z2);
    tail<<<2304, 256, 0, stream>>>(Z2, WoutT, outp, out + OFF_OUT,
                                   (const f32x4*)tin, (const f32x4*)inputs,
                                   (const f32x4*)trec, (const f32x4*)z,
                                   (f32x4*)(out + OFF_TIN), (f32x4*)(out + OFF_TREC));
  } else {
    fb_trace<<<2048, 256, 0, stream>>>((const float4*)tin, (const float4*)inputs,
                                       (const float4*)trec, (const float4*)z,
                                       (float4*)(out + OFF_TIN), (float4*)(out + OFF_TREC));
    fb_gemm<0><<<dim3(16, 16), 256, 0, stream>>>(inputs, z, w_in, w_rec, v, z, r, out);
    fb_gemm<1><<<dim3(8, 32), 256, 0, stream>>>(out + OFF_Z, nullptr, w_out, nullptr,
                                                outp, nullptr, nullptr, out);
  }
}